// Round 3
// baseline (882.639 us; speedup 1.0000x reference)
//
#include <hip/hip_runtime.h>
#include <stdint.h>

// Problem constants (from reference setup_inputs) — ALL TENSORS ARE FLOAT32.
#define T_STEPS 100
#define BATCH   65536
#define NI      2
#define NH      10
#define NO      4
#define KCH     10   // time chunks; block's chunk = blockIdx.x % KCH
#define TC      10   // steps per chunk; KCH*TC == T_STEPS

typedef float vf2 __attribute__((ext_vector_type(2)));
typedef float vf4 __attribute__((ext_vector_type(4)));

// Uniform (wave-invariant) load forced into an SGPR: keeps the 74 weight
// scalars out of the VGPR budget so __launch_bounds__(256,4) (128-VGPR cap)
// holds without scratch spills.
__device__ __forceinline__ float uload(const float* p) {
    return __uint_as_float((uint32_t)__builtin_amdgcn_readfirstlane((int)__float_as_uint(*p)));
}

#define LOAD_WEIGHTS                                                        \
    float w1[NH][NI], bb1[NH], w2[NO][NH], bb2[NO];                         \
    _Pragma("unroll") for (int h = 0; h < NH; ++h) {                        \
        w1[h][0] = uload(&W1[h * NI + 0]);                                  \
        w1[h][1] = uload(&W1[h * NI + 1]);                                  \
        bb1[h]   = uload(&b1[h]);                                           \
    }                                                                       \
    _Pragma("unroll") for (int o = 0; o < NO; ++o) {                        \
        _Pragma("unroll") for (int h = 0; h < NH; ++h)                      \
            w2[o][h] = uload(&W2[o * NH + h]);                              \
        bb2[o] = uload(&b2[o]);                                             \
    }

// One LIF timestep for both layers. EXACT arithmetic order of the
// harness-verified kernel (fmaf ascending-k, 0.5*m exact, reset exact):
// any change here changes absmax vs the reference.
__device__ __forceinline__ void lif_step(
    const float x0, const float x1,
    const float w1[NH][NI], const float bb1[NH],
    const float w2[NO][NH], const float bb2[NO],
    float m1[NH], float m2[NO], float spk1[NH], float spk2[NO])
{
#pragma unroll
    for (int h = 0; h < NH; ++h) {
        float syn   = __builtin_fmaf(x1, w1[h][1], x0 * w1[h][0]) + bb1[h];
        float reset = (m1[h] > 1.0f) ? 1.0f : 0.0f;   // pre-update membrane, detached
        float m     = 0.5f * m1[h] + syn;
        m           = m - reset;
        m1[h]       = m;
        spk1[h]     = ((m - 1.0f) > 0.0f) ? 1.0f : 0.0f;
    }
#pragma unroll
    for (int o = 0; o < NO; ++o) {
        float acc = spk1[0] * w2[o][0];
#pragma unroll
        for (int h = 1; h < NH; ++h) acc = __builtin_fmaf(spk1[h], w2[o][h], acc);
        float syn   = acc + bb2[o];
        float reset = (m2[o] > 1.0f) ? 1.0f : 0.0f;
        float m     = 0.5f * m2[o] + syn;
        m           = m - reset;
        m2[o]       = m;
        spk2[o]     = ((m - 1.0f) > 0.0f) ? 1.0f : 0.0f;
    }
}

// ---------------------------------------------------------------------------
// Single fused kernel. Block handles time chunk k = blockIdx.x % KCH for
// batch slice bb = blockIdx.x / KCH (k interleaved so each CU hosts mixed-k
// blocks: late-k blocks are in their VALU-only scan phase while early-k
// blocks saturate store bandwidth).
//
// Phase 1 (scan): recompute state from t=0 to k*10-1. No stores. x re-reads
// across blocks hit L3 (x = 52 MB << 256 MB Infinity Cache), so HBM fetch
// stays ~1x. VALU cost <= 8.3 us for k=9 — cheaper than the checkpoint
// round-trip + kernel serialization it replaces.
//
// Phase 2 (emit): 10 steps, all four outputs stored. NH-sized rows go
// through a wave-local LDS transpose (no s_barrier needed: DS ops are
// in-order within a wave) so every global store is a fully-coalesced
// contiguous dwordx4/dwordx2 pass instead of 8B-at-40B-stride partial lines.
// ---------------------------------------------------------------------------
__global__ __launch_bounds__(256, 4) void snn_all(
    const float* __restrict__ x, const float* __restrict__ W1,
    const float* __restrict__ b1, const float* __restrict__ W2,
    const float* __restrict__ b2, float* __restrict__ out)
{
    LOAD_WEIGHTS;

    const int tid  = threadIdx.x;
    const int k    = blockIdx.x % KCH;         // time chunk 0..9 (interleaved)
    const int bb   = blockIdx.x / KCH;         // batch block 0..255
    const int b    = bb * 256 + tid;
    const int w    = tid >> 6;
    const int lane = tid & 63;
    const int wb0  = bb * 256 + (w << 6);      // wave's first batch element

    const size_t sec = (size_t)T_STEPS * BATCH;
    float* o_spk1 = out;
    float* o_mem1 = out + sec * NH;
    float* o_spk2 = out + 2 * sec * NH;
    float* o_mem2 = out + 2 * sec * NH + sec * NO;

    // Rolling x buffer, depth 10, static indexing (never scratch-allocated).
    const vf2* xp = (const vf2*)x + b;
    vf2 xb[TC];
#pragma unroll
    for (int j = 0; j < TC; ++j) xb[j] = xp[(size_t)j * BATCH];

    float m1[NH], m2[NO];
#pragma unroll
    for (int h = 0; h < NH; ++h) m1[h] = 0.0f;
#pragma unroll
    for (int o = 0; o < NO; ++o) m2[o] = 0.0f;

    // ---- Phase 1: store-free recompute of steps [0, k*10). After chunk tt,
    // xb[j] holds x[tt+10+j]; on loop exit xb[j] = x[k*10+j] (emit inputs).
    for (int tt = 0; tt < k * TC; tt += TC) {
#pragma unroll
        for (int j = 0; j < TC; ++j) {
            float spk1[NH], spk2[NO];
            lif_step(xb[j].x, xb[j].y, w1, bb1, w2, bb2, m1, m2, spk1, spk2);
            xb[j] = xp[(size_t)(tt + TC + j) * BATCH];   // <= x[k*10+9], in range
        }
    }

    // Per-wave staging: [wave][spk/mem][160 vf4] = 2560B per array per wave.
    __shared__ vf4 stage[4][2][160];           // 20480 B/block -> 8 blocks/CU LDS-wise
    float* s_spk = (float*)&stage[w][0][0];
    float* s_mem = (float*)&stage[w][1][0];

    // ---- Phase 2: emit steps t = k*10 .. k*10+9 with all outputs.
#pragma unroll
    for (int j = 0; j < TC; ++j) {
        const int t = k * TC + j;
        float spk1[NH], spk2[NO];
        lif_step(xb[j].x, xb[j].y, w1, bb1, w2, bb2, m1, m2, spk1, spk2);

        // Stage NH outputs into wave-local LDS (5x ds_write_b64 each).
        {
            vf2* qs = (vf2*)s_spk;
            vf2* qm = (vf2*)s_mem;
#pragma unroll
            for (int i = 0; i < NH / 2; ++i) {
                vf2 vs; vs.x = spk1[2 * i]; vs.y = spk1[2 * i + 1];
                vf2 vm; vm.x = m1[2 * i];   vm.y = m1[2 * i + 1];
                qs[lane * 5 + i] = vs;
                qm[lane * 5 + i] = vm;
            }
        }
        __builtin_amdgcn_wave_barrier();

        // Coalesced store of each wave's 2560B region: 2x dwordx4 + 1x dwordx2.
        {
            float* g = o_spk1 + (size_t)t * BATCH * NH + (size_t)wb0 * NH;
            vf4* g4 = (vf4*)g;
            g4[lane]      = stage[w][0][lane];
            g4[64 + lane] = stage[w][0][64 + lane];
            ((vf2*)g)[256 + lane] = ((vf2*)s_spk)[256 + lane];
        }
        {
            float* g = o_mem1 + (size_t)t * BATCH * NH + (size_t)wb0 * NH;
            vf4* g4 = (vf4*)g;
            g4[lane]      = stage[w][1][lane];
            g4[64 + lane] = stage[w][1][64 + lane];
            ((vf2*)g)[256 + lane] = ((vf2*)s_mem)[256 + lane];
        }
        __builtin_amdgcn_wave_barrier();

        // NO outputs: 16B/lane at 16B stride -> already fully coalesced.
        {
            vf4 vs; vs.x = spk2[0]; vs.y = spk2[1]; vs.z = spk2[2]; vs.w = spk2[3];
            vf4 vm; vm.x = m2[0];   vm.y = m2[1];   vm.z = m2[2];   vm.w = m2[3];
            *(vf4*)(o_spk2 + ((size_t)t * BATCH + b) * NO) = vs;
            *(vf4*)(o_mem2 + ((size_t)t * BATCH + b) * NO) = vm;
        }
    }
}

extern "C" void kernel_launch(void* const* d_in, const int* in_sizes, int n_in,
                              void* d_out, int out_size, void* d_ws, size_t ws_size,
                              hipStream_t stream) {
    const float* x  = (const float*)d_in[0];
    const float* W1 = (const float*)d_in[1];
    const float* b1 = (const float*)d_in[2];
    const float* W2 = (const float*)d_in[3];
    const float* b2 = (const float*)d_in[4];
    float* out = (float*)d_out;

    // One dispatch: 2560 blocks (10 chunks x 256 batch-blocks, k-interleaved).
    snn_all<<<(BATCH / 256) * KCH, 256, 0, stream>>>(x, W1, b1, W2, b2, out);
}

// Round 5
// 795.571 us; speedup vs baseline: 1.1094x; 1.1094x over previous
//
#include <hip/hip_runtime.h>
#include <stdint.h>

// Problem constants (from reference setup_inputs) — ALL TENSORS ARE FLOAT32.
#define T_STEPS 100
#define BATCH   65536
#define NI      2
#define NH      10
#define NO      4
#define KCH     5    // time chunks; block's chunk = blockIdx.x % KCH
#define TC      20   // steps per chunk; KCH*TC == T_STEPS
#define GS      4    // steps per staging group (LDS granularity)
#define GPC     (TC / GS)   // 5 groups per chunk

typedef float vf2 __attribute__((ext_vector_type(2)));
typedef float vf4 __attribute__((ext_vector_type(4)));

// Uniform (wave-invariant) load forced into an SGPR: keeps the 74 weight
// scalars out of the VGPR budget (no scratch spills in the unrolled loops).
__device__ __forceinline__ float uload(const float* p) {
    return __uint_as_float((uint32_t)__builtin_amdgcn_readfirstlane((int)__float_as_uint(*p)));
}

#define LOAD_WEIGHTS                                                        \
    float w1[NH][NI], bb1[NH], w2[NO][NH], bb2[NO];                         \
    _Pragma("unroll") for (int h = 0; h < NH; ++h) {                        \
        w1[h][0] = uload(&W1[h * NI + 0]);                                  \
        w1[h][1] = uload(&W1[h * NI + 1]);                                  \
        bb1[h]   = uload(&b1[h]);                                           \
    }                                                                       \
    _Pragma("unroll") for (int o = 0; o < NO; ++o) {                        \
        _Pragma("unroll") for (int h = 0; h < NH; ++h)                      \
            w2[o][h] = uload(&W2[o * NH + h]);                              \
        bb2[o] = uload(&b2[o]);                                             \
    }

// One LIF timestep for both layers. EXACT arithmetic order of the
// harness-verified kernel (fmaf ascending-k, 0.5*m exact, reset exact):
// any change here changes absmax vs the reference.
__device__ __forceinline__ void lif_step(
    const float x0, const float x1,
    const float w1[NH][NI], const float bb1[NH],
    const float w2[NO][NH], const float bb2[NO],
    float m1[NH], float m2[NO], float spk1[NH], float spk2[NO])
{
#pragma unroll
    for (int h = 0; h < NH; ++h) {
        float syn   = __builtin_fmaf(x1, w1[h][1], x0 * w1[h][0]) + bb1[h];
        float reset = (m1[h] > 1.0f) ? 1.0f : 0.0f;   // pre-update membrane, detached
        float m     = 0.5f * m1[h] + syn;
        m           = m - reset;
        m1[h]       = m;
        spk1[h]     = ((m - 1.0f) > 0.0f) ? 1.0f : 0.0f;
    }
#pragma unroll
    for (int o = 0; o < NO; ++o) {
        float acc = spk1[0] * w2[o][0];
#pragma unroll
        for (int h = 1; h < NH; ++h) acc = __builtin_fmaf(spk1[h], w2[o][h], acc);
        float syn   = acc + bb2[o];
        float reset = (m2[o] > 1.0f) ? 1.0f : 0.0f;
        float m     = 0.5f * m2[o] + syn;
        m           = m - reset;
        m2[o]       = m;
        spk2[o]     = ((m - 1.0f) > 0.0f) ? 1.0f : 0.0f;
    }
}

// ---------------------------------------------------------------------------
// Single fused kernel, store-decoupled.
//
// Block = (chunk k, batch slice bb). Phase 1: store-free recompute of steps
// [0, k*TC) — x re-reads served by L3 (52 MB << 256 MB). Phase 2: per group
// of GS=4 steps: (a) COMPUTE, writing spk1/mem1 into an 80 KiB LDS staging
// block and spk2/mem2 into registers — zero global traffic, so no vmcnt
// stalls in the dependency chain; (b) BULK STORE: a pure streaming pass of
// linear LDS reads + 32 coalesced wave-stores with no intervening waits —
// the vmcnt drain overlaps the NEXT group's compute (register reuse is one
// full compute phase away). This mimics the dependency structure of the
// harness fill kernel, which sustains 6.28 TB/s at 10% occupancy.
//
// Each wave reads back only its own lanes' staging rows -> wave-internal
// DS ordering suffices, no barriers at all.
// ---------------------------------------------------------------------------
__global__ __launch_bounds__(256, 2) void snn_fused(
    const float* __restrict__ x, const float* __restrict__ W1,
    const float* __restrict__ b1, const float* __restrict__ W2,
    const float* __restrict__ b2, float* __restrict__ out)
{
    LOAD_WEIGHTS;

    const int tid  = threadIdx.x;
    const int k    = blockIdx.x % KCH;         // chunk 0..4 (interleaved for CU mixing)
    const int bb   = blockIdx.x / KCH;         // batch block 0..255
    const int b    = bb * 256 + tid;
    const int w    = tid >> 6;
    const int lane = tid & 63;
    const int wb0  = bb * 256 + (w << 6);      // wave's first batch element

    const size_t sec = (size_t)T_STEPS * BATCH;
    float* o_spk1 = out;
    float* o_mem1 = out + sec * NH;
    float* o_spk2 = out + 2 * sec * NH;
    float* o_mem2 = out + 2 * sec * NH + sec * NO;

    const vf2* xp = (const vf2*)x + b;

    float m1[NH], m2[NO];
#pragma unroll
    for (int h = 0; h < NH; ++h) m1[h] = 0.0f;
#pragma unroll
    for (int o = 0; o < NO; ++o) m2[o] = 0.0f;

    const int Gscan = k * GPC;                 // store-free groups
    const int G     = Gscan + GPC;             // total groups (5..25)

    // x pipeline: current group + next group in registers (depth 8 steps,
    // covers L3 latency). All static indexing.
    vf2 xc[GS], xn[GS];
#pragma unroll
    for (int i = 0; i < GS; ++i) xc[i] = xp[(size_t)i * BATCH];
#pragma unroll
    for (int i = 0; i < GS; ++i) xn[i] = xp[(size_t)(GS + i) * BATCH];

    // Staging: exactly 80 KiB -> 2 blocks/CU. Layout [step][elem][h] matches
    // the global [elem][h] order so the bulk pass is a linear copy.
    __shared__ float sA[GS][256][NH];          // spk1
    __shared__ float sB[GS][256][NH];          // mem1

    vf4 s2r[GS], m2r[GS];                      // spk2/mem2 register staging

    for (int g = 0; g < G; ++g) {
        if (g < Gscan) {
            // ---- scan: state update only, nothing emitted.
#pragma unroll
            for (int j = 0; j < GS; ++j) {
                float spk1[NH], spk2[NO];
                lif_step(xc[j].x, xc[j].y, w1, bb1, w2, bb2, m1, m2, spk1, spk2);
            }
        } else {
            // ---- compute phase: 4 steps, outputs to LDS/regs only.
#pragma unroll
            for (int j = 0; j < GS; ++j) {
                float spk1[NH], spk2[NO];
                lif_step(xc[j].x, xc[j].y, w1, bb1, w2, bb2, m1, m2, spk1, spk2);
                vf2* qa = (vf2*)&sA[j][tid][0];
                vf2* qb = (vf2*)&sB[j][tid][0];
#pragma unroll
                for (int i = 0; i < NH / 2; ++i) {
                    vf2 vs; vs.x = spk1[2 * i]; vs.y = spk1[2 * i + 1];
                    vf2 vm; vm.x = m1[2 * i];   vm.y = m1[2 * i + 1];
                    qa[i] = vs;
                    qb[i] = vm;
                }
                vf4 v2; v2.x = spk2[0]; v2.y = spk2[1]; v2.z = spk2[2]; v2.w = spk2[3];
                vf4 vm2; vm2.x = m2[0]; vm2.y = m2[1]; vm2.z = m2[2]; vm2.w = m2[3];
                s2r[j] = v2;
                m2r[j] = vm2;
            }
            __builtin_amdgcn_wave_barrier();   // keep DS write/read program order

            // ---- bulk store phase: streaming, no waits between stores.
            const int t0g = k * TC + (g - Gscan) * GS;
#pragma unroll
            for (int j = 0; j < GS; ++j) {
                const int t = t0g + j;
                {   // spk1: wave's 2560B staging region -> contiguous global run
                    const float* ls = &sA[j][w * 64][0];
                    vf4 r0 = ((const vf4*)ls)[lane];
                    vf4 r1 = ((const vf4*)ls)[64 + lane];
                    vf2 r2 = ((const vf2*)ls)[256 + lane];
                    float* gd = o_spk1 + ((size_t)t * BATCH + wb0) * NH;
                    ((vf4*)gd)[lane]      = r0;
                    ((vf4*)gd)[64 + lane] = r1;
                    ((vf2*)gd)[256 + lane] = r2;
                }
                {   // mem1
                    const float* ls = &sB[j][w * 64][0];
                    vf4 r0 = ((const vf4*)ls)[lane];
                    vf4 r1 = ((const vf4*)ls)[64 + lane];
                    vf2 r2 = ((const vf2*)ls)[256 + lane];
                    float* gd = o_mem1 + ((size_t)t * BATCH + wb0) * NH;
                    ((vf4*)gd)[lane]      = r0;
                    ((vf4*)gd)[64 + lane] = r1;
                    ((vf2*)gd)[256 + lane] = r2;
                }
                // spk2/mem2: 16B/lane at 16B stride, already coalesced.
                *(vf4*)(o_spk2 + ((size_t)t * BATCH + b) * NO) = s2r[j];
                *(vf4*)(o_mem2 + ((size_t)t * BATCH + b) * NO) = m2r[j];
            }
            __builtin_amdgcn_wave_barrier();
        }

        // ---- advance x pipeline (guarded; max needed group is G-1).
#pragma unroll
        for (int i = 0; i < GS; ++i) xc[i] = xn[i];
        if (g + 2 < G) {
#pragma unroll
            for (int i = 0; i < GS; ++i)
                xn[i] = xp[(size_t)((g + 2) * GS + i) * BATCH];
        }
    }
}

extern "C" void kernel_launch(void* const* d_in, const int* in_sizes, int n_in,
                              void* d_out, int out_size, void* d_ws, size_t ws_size,
                              hipStream_t stream) {
    const float* x  = (const float*)d_in[0];
    const float* W1 = (const float*)d_in[1];
    const float* b1 = (const float*)d_in[2];
    const float* W2 = (const float*)d_in[3];
    const float* b2 = (const float*)d_in[4];
    float* out = (float*)d_out;

    // One dispatch: 1280 blocks (5 chunks x 256 batch-blocks, k-interleaved).
    snn_fused<<<(BATCH / 256) * KCH, 256, 0, stream>>>(x, W1, b1, W2, b2, out);
}